// Round 6
// baseline (171.756 us; speedup 1.0000x reference)
//
#include <hip/hip_runtime.h>

#define B 8
#define CCH 3
#define HH 512
#define WW 512
#define HW (HH * WW)
#define WIN 21
#define PAD 10
#define TSX 32
#define TSY 32
#define PTY 52                 // TSY + 2*PAD rows staged
#define TROW 60                // tile row stride (dwords): 28r+4c sweeps all 32 banks
#define HSH 53                 // hs rows per column
#define NSLOT 676              // 52 rows x 13 float4 groups
#define NGRP 2                 // batch groups (blocks per output tile)
#define BPG 4                  // batches per group

// lgkm-only barrier: orders LDS producer/consumer without draining vmcnt,
// so cross-batch global prefetches stay in flight across barriers.
__device__ __forceinline__ void lds_barrier() {
    asm volatile("s_waitcnt lgkmcnt(0)" ::: "memory");
    __builtin_amdgcn_s_barrier();
    asm volatile("" ::: "memory");
}

__global__ __launch_bounds__(256, 6) void nlm_part_kernel(const float* __restrict__ noisy,
                                                          float* __restrict__ out) {
    __shared__ float  tile[PTY][TROW];     // 12480 B
    __shared__ float2 hs_t[TSX][HSH];      // 13568 B  -> 26 KB: 6 blocks/CU

    const int tid = threadIdx.x;
    const int x0 = blockIdx.x * TSX;
    const int y0 = blockIdx.y * TSY;
    const int zz = blockIdx.z;             // 0..5
    const int g  = zz / CCH;               // batch group 0/1
    const int ch = zz - g * CCH;

    // ---- precompute staging slots (addresses batch-invariant) ----
    int   rowbase[3], gxs[3];
    float* ldsp[3];
    bool  valid[3], edge[3];
    #pragma unroll
    for (int k = 0; k < 3; ++k) {
        int s = tid + 256 * k;
        valid[k] = (s < NSLOT);
        int ss = valid[k] ? s : 0;
        int r  = ss / 13;
        int c4 = ss - r * 13;
        int gy = y0 + r - PAD;
        gy = (gy < 0) ? -gy : ((gy >= HH) ? (2 * (HH - 1) - gy) : gy);
        int gx = x0 + (c4 << 2) - PAD;
        rowbase[k] = gy * WW;
        gxs[k]     = gx;
        edge[k]    = (gx < 0) || (gx > WW - 4);
        ldsp[k]    = &tile[r][c4 << 2];
    }

    const int b0 = g * BPG;
    const float* src0 = noisy + (size_t)(b0 * CCH + ch) * HW;
    float4 pre[3];
    // prefetch first batch of this group
    #pragma unroll
    for (int k = 0; k < 3; ++k) {
        if (valid[k]) {
            if (!edge[k]) {
                pre[k] = *(const float4*)(src0 + rowbase[k] + gxs[k]);
            } else {
                float tmp[4];
                #pragma unroll
                for (int t = 0; t < 4; ++t) {
                    int gx = gxs[k] + t;
                    gx = (gx < 0) ? -gx : ((gx >= WW) ? (2 * (WW - 1) - gx) : gx);
                    tmp[t] = src0[rowbase[k] + gx];
                }
                pre[k] = make_float4(tmp[0], tmp[1], tmp[2], tmp[3]);
            }
        }
    }

    float num[4] = {0.f, 0.f, 0.f, 0.f};
    float den[4] = {0.f, 0.f, 0.f, 0.f};

    const int tx  = tid & 31;
    const int ty0 = (tid >> 5) << 2;       // 4 consecutive output rows / thread
    const float kE = (-100.0f / 441.0f) * 1.44269504088896f;  // fold 1/h^2/n/ln2

    for (int lb = 0; lb < BPG; ++lb) {
        lds_barrier();                     // Btop: previous V's tile/hs reads done
        #pragma unroll
        for (int k = 0; k < 3; ++k)
            if (valid[k]) *(float4*)ldsp[k] = pre[k];
        lds_barrier();                     // B1: tile visible

        // issue next batch's global loads now; in flight across H+V+Btop
        if (lb < BPG - 1) {
            const float* srcn = noisy + (size_t)((b0 + lb + 1) * CCH + ch) * HW;
            #pragma unroll
            for (int k = 0; k < 3; ++k) {
                if (valid[k]) {
                    if (!edge[k]) {
                        pre[k] = *(const float4*)(srcn + rowbase[k] + gxs[k]);
                    } else {
                        float tmp[4];
                        #pragma unroll
                        for (int t = 0; t < 4; ++t) {
                            int gx = gxs[k] + t;
                            gx = (gx < 0) ? -gx : ((gx >= WW) ? (2 * (WW - 1) - gx) : gx);
                            tmp[t] = srcn[rowbase[k] + gx];
                        }
                        pre[k] = make_float4(tmp[0], tmp[1], tmp[2], tmp[3]);
                    }
                }
            }
        }

        // ---- horizontal box sums: 52 rows x 4 segments of 8 output cols ----
        if (tid < PTY * 4) {
            int r   = tid >> 2;
            int cx0 = (tid & 3) << 3;      // 0,8,16,24
            float v[28];
            #pragma unroll
            for (int q = 0; q < 7; ++q)
                *(float4*)&v[q * 4] = *(const float4*)&tile[r][cx0 + (q << 2)];
            float s1 = 0.f, s2 = 0.f;
            #pragma unroll
            for (int k = 0; k <= 20; ++k) { s1 += v[k]; s2 = fmaf(v[k], v[k], s2); }
            hs_t[cx0][r] = make_float2(s1, s2);
            #pragma unroll
            for (int j = 1; j < 8; ++j) {
                float vo = v[j - 1], vn = v[j + 20];
                s1 += vn - vo;
                s2 += vn * vn - vo * vo;
                hs_t[cx0 + j][r] = make_float2(s1, s2);
            }
        }
        lds_barrier();                     // B2: hs visible

        // ---- vertical sliding sums: 4 output rows per thread ----
        float2 h0 = hs_t[tx][ty0];
        float2 h1 = hs_t[tx][ty0 + 1];
        float2 h2 = hs_t[tx][ty0 + 2];
        float vs1 = h0.x + h1.x + h2.x;
        float vs2 = h0.y + h1.y + h2.y;
        #pragma unroll
        for (int k = 3; k <= 20; ++k) {
            float2 h = hs_t[tx][ty0 + k];
            vs1 += h.x;
            vs2 += h.y;
        }
        {
            float a = tile[ty0 + PAD][tx + PAD];
            float p = tile[ty0][tx];
            float dd = fmaf(a, fmaf(441.f, a, -2.f * vs1), vs2);
            float w = exp2f(dd * kE);
            num[0] += w * p; den[0] += w;
        }
        #pragma unroll
        for (int i = 1; i < 4; ++i) {
            float2 hn = hs_t[tx][ty0 + 20 + i];
            float2 ho = (i == 1) ? h0 : ((i == 2) ? h1 : h2);
            vs1 += hn.x - ho.x;
            vs2 += hn.y - ho.y;
            float a = tile[ty0 + i + PAD][tx + PAD];
            float p = tile[ty0 + i][tx];
            float dd = fmaf(a, fmaf(441.f, a, -2.f * vs1), vs2);
            float w = exp2f(dd * kE);
            num[i] += w * p; den[i] += w;
        }
    }

    // ---- write this group's partials into output slices b = 2g, 2g+1 ----
    // (no fences, no atomics: the kernel boundary orders k1 -> k2)
    const int y = y0 + ty0;
    const int x = x0 + tx;
    const size_t sliceN = ((size_t)((g * 2 + 0) * CCH + ch)) * HW;
    const size_t sliceD = ((size_t)((g * 2 + 1) * CCH + ch)) * HW;
    #pragma unroll
    for (int i = 0; i < 4; ++i) {
        out[sliceN + (size_t)(y + i) * WW + x] = num[i];
        out[sliceD + (size_t)(y + i) * WW + x] = den[i];
    }
}

__global__ __launch_bounds__(256) void nlm_combine_kernel(float* __restrict__ out) {
    const size_t S = (size_t)CCH * HW;                       // one batch slice (3 ch)
    const size_t p = ((size_t)blockIdx.x * 256 + threadIdx.x) * 4;
    float4 n1 = *(const float4*)(out + 0 * S + p);
    float4 d1 = *(const float4*)(out + 1 * S + p);
    float4 n2 = *(const float4*)(out + 2 * S + p);
    float4 d2 = *(const float4*)(out + 3 * S + p);
    float4 r;
    r.x = (n1.x + n2.x) / ((d1.x + d2.x) + 1e-10f);
    r.y = (n1.y + n2.y) / ((d1.y + d2.y) + 1e-10f);
    r.z = (n1.z + n2.z) / ((d1.z + d2.z) + 1e-10f);
    r.w = (n1.w + n2.w) / ((d1.w + d2.w) + 1e-10f);
    r.x = r.x < 0.f ? 0.f : (r.x > 1.f ? 1.f : r.x);
    r.y = r.y < 0.f ? 0.f : (r.y > 1.f ? 1.f : r.y);
    r.z = r.z < 0.f ? 0.f : (r.z > 1.f ? 1.f : r.z);
    r.w = r.w < 0.f ? 0.f : (r.w > 1.f ? 1.f : r.w);
    #pragma unroll
    for (int b = 0; b < B; ++b)
        *(float4*)(out + (size_t)b * S + p) = r;
}

extern "C" void kernel_launch(void* const* d_in, const int* in_sizes, int n_in,
                              void* d_out, int out_size, void* d_ws, size_t ws_size,
                              hipStream_t stream) {
    const float* noisy = (const float*)d_in[0];
    float* out = (float*)d_out;
    dim3 grid1(WW / TSX, HH / TSY, CCH * NGRP);              // 1536 blocks
    nlm_part_kernel<<<grid1, dim3(256), 0, stream>>>(noisy, out);
    const int nq = (CCH * HW) / 4 / 256;                     // 768 blocks
    nlm_combine_kernel<<<dim3(nq), dim3(256), 0, stream>>>(out);
}

// Round 7
// 131.798 us; speedup vs baseline: 1.3032x; 1.3032x over previous
//
#include <hip/hip_runtime.h>

#define B 8
#define CCH 3
#define HH 512
#define WW 512
#define HW (HH * WW)
#define WIN 21
#define PAD 10
#define TSX 32
#define TSY 32
#define PTY 52                 // TSY + 2*PAD rows staged
#define TROW 60                // tile row stride (dwords): 28r+4c sweeps all 32 banks
#define HSH 53                 // hs rows per column
#define NSLOT 676              // 52 rows x 13 float4 groups
#define NGRP 2                 // batch groups (blocks per output tile)
#define BPG 4                  // batches per group

// lgkm-only barrier: orders LDS producer/consumer without draining vmcnt,
// so cross-batch global prefetches stay in flight across barriers.
__device__ __forceinline__ void lds_barrier() {
    asm volatile("s_waitcnt lgkmcnt(0)" ::: "memory");
    __builtin_amdgcn_s_barrier();
    asm volatile("" ::: "memory");
}

// min-waves 4 (NOT 6): r6 proved (256,6) caps VGPR at 40 -> massive scratch
// spill (WRITE 242 MB). At (256,4) this body compiles to ~64 VGPR, no spill
// (r4 evidence); occupancy is then LDS-limited at 6 blocks/CU anyway.
__global__ __launch_bounds__(256, 4) void nlm_part_kernel(const float* __restrict__ noisy,
                                                          float* __restrict__ out) {
    __shared__ float  tile[PTY][TROW];     // 12480 B
    __shared__ float2 hs_t[TSX][HSH];      // 13568 B  -> 26 KB: 6 blocks/CU

    const int tid = threadIdx.x;
    const int x0 = blockIdx.x * TSX;
    const int y0 = blockIdx.y * TSY;
    const int zz = blockIdx.z;             // 0..5
    const int g  = zz / CCH;               // batch group 0/1
    const int ch = zz - g * CCH;

    // ---- precompute staging slots (addresses batch-invariant) ----
    int   rowbase[3], gxs[3];
    float* ldsp[3];
    bool  valid[3], edge[3];
    #pragma unroll
    for (int k = 0; k < 3; ++k) {
        int s = tid + 256 * k;
        valid[k] = (s < NSLOT);
        int ss = valid[k] ? s : 0;
        int r  = ss / 13;
        int c4 = ss - r * 13;
        int gy = y0 + r - PAD;
        gy = (gy < 0) ? -gy : ((gy >= HH) ? (2 * (HH - 1) - gy) : gy);
        int gx = x0 + (c4 << 2) - PAD;
        rowbase[k] = gy * WW;
        gxs[k]     = gx;
        edge[k]    = (gx < 0) || (gx > WW - 4);
        ldsp[k]    = &tile[r][c4 << 2];
    }

    const int b0 = g * BPG;
    const float* src0 = noisy + (size_t)(b0 * CCH + ch) * HW;
    float4 pre[3];
    // prefetch first batch of this group
    #pragma unroll
    for (int k = 0; k < 3; ++k) {
        if (valid[k]) {
            if (!edge[k]) {
                pre[k] = *(const float4*)(src0 + rowbase[k] + gxs[k]);
            } else {
                float tmp[4];
                #pragma unroll
                for (int t = 0; t < 4; ++t) {
                    int gx = gxs[k] + t;
                    gx = (gx < 0) ? -gx : ((gx >= WW) ? (2 * (WW - 1) - gx) : gx);
                    tmp[t] = src0[rowbase[k] + gx];
                }
                pre[k] = make_float4(tmp[0], tmp[1], tmp[2], tmp[3]);
            }
        }
    }

    float num[4] = {0.f, 0.f, 0.f, 0.f};
    float den[4] = {0.f, 0.f, 0.f, 0.f};

    const int tx  = tid & 31;
    const int ty0 = (tid >> 5) << 2;       // 4 consecutive output rows / thread
    const float kE = (-100.0f / 441.0f) * 1.44269504088896f;  // fold 1/h^2/n/ln2

    for (int lb = 0; lb < BPG; ++lb) {
        lds_barrier();                     // Btop: previous V's tile/hs reads done
        #pragma unroll
        for (int k = 0; k < 3; ++k)
            if (valid[k]) *(float4*)ldsp[k] = pre[k];
        lds_barrier();                     // B1: tile visible

        // issue next batch's global loads now; in flight across H+V+Btop
        if (lb < BPG - 1) {
            const float* srcn = noisy + (size_t)((b0 + lb + 1) * CCH + ch) * HW;
            #pragma unroll
            for (int k = 0; k < 3; ++k) {
                if (valid[k]) {
                    if (!edge[k]) {
                        pre[k] = *(const float4*)(srcn + rowbase[k] + gxs[k]);
                    } else {
                        float tmp[4];
                        #pragma unroll
                        for (int t = 0; t < 4; ++t) {
                            int gx = gxs[k] + t;
                            gx = (gx < 0) ? -gx : ((gx >= WW) ? (2 * (WW - 1) - gx) : gx);
                            tmp[t] = srcn[rowbase[k] + gx];
                        }
                        pre[k] = make_float4(tmp[0], tmp[1], tmp[2], tmp[3]);
                    }
                }
            }
        }

        // ---- horizontal box sums: 52 rows x 4 segments of 8 output cols ----
        if (tid < PTY * 4) {
            int r   = tid >> 2;
            int cx0 = (tid & 3) << 3;      // 0,8,16,24
            float v[28];
            #pragma unroll
            for (int q = 0; q < 7; ++q)
                *(float4*)&v[q * 4] = *(const float4*)&tile[r][cx0 + (q << 2)];
            float s1 = 0.f, s2 = 0.f;
            #pragma unroll
            for (int k = 0; k <= 20; ++k) { s1 += v[k]; s2 = fmaf(v[k], v[k], s2); }
            hs_t[cx0][r] = make_float2(s1, s2);
            #pragma unroll
            for (int j = 1; j < 8; ++j) {
                float vo = v[j - 1], vn = v[j + 20];
                s1 += vn - vo;
                s2 += vn * vn - vo * vo;
                hs_t[cx0 + j][r] = make_float2(s1, s2);
            }
        }
        lds_barrier();                     // B2: hs visible

        // ---- vertical sliding sums: 4 output rows per thread ----
        float2 h0 = hs_t[tx][ty0];
        float2 h1 = hs_t[tx][ty0 + 1];
        float2 h2 = hs_t[tx][ty0 + 2];
        float vs1 = h0.x + h1.x + h2.x;
        float vs2 = h0.y + h1.y + h2.y;
        #pragma unroll
        for (int k = 3; k <= 20; ++k) {
            float2 h = hs_t[tx][ty0 + k];
            vs1 += h.x;
            vs2 += h.y;
        }
        {
            float a = tile[ty0 + PAD][tx + PAD];
            float p = tile[ty0][tx];
            float dd = fmaf(a, fmaf(441.f, a, -2.f * vs1), vs2);
            float w = exp2f(dd * kE);
            num[0] += w * p; den[0] += w;
        }
        #pragma unroll
        for (int i = 1; i < 4; ++i) {
            float2 hn = hs_t[tx][ty0 + 20 + i];
            float2 ho = (i == 1) ? h0 : ((i == 2) ? h1 : h2);
            vs1 += hn.x - ho.x;
            vs2 += hn.y - ho.y;
            float a = tile[ty0 + i + PAD][tx + PAD];
            float p = tile[ty0 + i][tx];
            float dd = fmaf(a, fmaf(441.f, a, -2.f * vs1), vs2);
            float w = exp2f(dd * kE);
            num[i] += w * p; den[i] += w;
        }
    }

    // ---- write this group's partials into output slices b = 2g, 2g+1 ----
    // (no fences, no atomics: the kernel boundary orders k1 -> k2)
    const int y = y0 + ty0;
    const int x = x0 + tx;
    const size_t sliceN = ((size_t)((g * 2 + 0) * CCH + ch)) * HW;
    const size_t sliceD = ((size_t)((g * 2 + 1) * CCH + ch)) * HW;
    #pragma unroll
    for (int i = 0; i < 4; ++i) {
        out[sliceN + (size_t)(y + i) * WW + x] = num[i];
        out[sliceD + (size_t)(y + i) * WW + x] = den[i];
    }
}

__global__ __launch_bounds__(256) void nlm_combine_kernel(float* __restrict__ out) {
    const size_t S = (size_t)CCH * HW;                       // one batch slice (3 ch)
    const size_t p = ((size_t)blockIdx.x * 256 + threadIdx.x) * 4;
    float4 n1 = *(const float4*)(out + 0 * S + p);
    float4 d1 = *(const float4*)(out + 1 * S + p);
    float4 n2 = *(const float4*)(out + 2 * S + p);
    float4 d2 = *(const float4*)(out + 3 * S + p);
    float4 r;
    r.x = (n1.x + n2.x) / ((d1.x + d2.x) + 1e-10f);
    r.y = (n1.y + n2.y) / ((d1.y + d2.y) + 1e-10f);
    r.z = (n1.z + n2.z) / ((d1.z + d2.z) + 1e-10f);
    r.w = (n1.w + n2.w) / ((d1.w + d2.w) + 1e-10f);
    r.x = r.x < 0.f ? 0.f : (r.x > 1.f ? 1.f : r.x);
    r.y = r.y < 0.f ? 0.f : (r.y > 1.f ? 1.f : r.y);
    r.z = r.z < 0.f ? 0.f : (r.z > 1.f ? 1.f : r.z);
    r.w = r.w < 0.f ? 0.f : (r.w > 1.f ? 1.f : r.w);
    #pragma unroll
    for (int b = 0; b < B; ++b)
        *(float4*)(out + (size_t)b * S + p) = r;
}

extern "C" void kernel_launch(void* const* d_in, const int* in_sizes, int n_in,
                              void* d_out, int out_size, void* d_ws, size_t ws_size,
                              hipStream_t stream) {
    const float* noisy = (const float*)d_in[0];
    float* out = (float*)d_out;
    dim3 grid1(WW / TSX, HH / TSY, CCH * NGRP);              // 1536 blocks
    nlm_part_kernel<<<grid1, dim3(256), 0, stream>>>(noisy, out);
    const int nq = (CCH * HW) / 4 / 256;                     // 768 blocks
    nlm_combine_kernel<<<dim3(nq), dim3(256), 0, stream>>>(out);
}

// Round 8
// 91.356 us; speedup vs baseline: 1.8801x; 1.4427x over previous
//
#include <hip/hip_runtime.h>

#define B 8
#define CCH 3
#define HH 512
#define WW 512
#define HW (HH * WW)
#define WIN 21
#define PAD 10
#define TSX 32
#define TSY 32
#define PTY 52                 // TSY + 2*PAD rows staged
#define TROW 60                // tile row stride (dwords): 28r+4c sweeps all 32 banks
#define HSH 53                 // hs rows per column
#define NSLOT 676              // 52 rows x 13 float4 groups
#define NTHR 512               // 8 waves/block: 3 blocks/CU -> 24 waves/CU resident
#define HTASK (PTY * 8)        // 416 horizontal tasks (4 output cols each)

// lgkm-only barrier: orders LDS producer/consumer without draining vmcnt,
// so cross-batch global prefetches stay in flight across barriers.
__device__ __forceinline__ void lds_barrier() {
    asm volatile("s_waitcnt lgkmcnt(0)" ::: "memory");
    __builtin_amdgcn_s_barrier();
    asm volatile("" ::: "memory");
}

// (512,3): VGPR cap ~170 -> zero spill risk (r6/r7 lesson: tight caps spill;
// body needs ~60-85). Occupancy is then LDS/VGPR-natural: 26 KB -> 3 blocks/CU
// of 8 waves each = 24 waves/CU if VGPR <= ~85.
__global__ __launch_bounds__(NTHR, 3) void nlm_fused_kernel(const float* __restrict__ noisy,
                                                            float* __restrict__ out) {
    __shared__ float  tile[PTY][TROW];     // 12480 B
    __shared__ float2 hs_t[TSX][HSH];      // 13568 B  -> 26 KB total

    const int tid = threadIdx.x;
    const int x0 = blockIdx.x * TSX;
    const int y0 = blockIdx.y * TSY;
    const int ch = blockIdx.z;

    // ---- precompute staging slots: 2 per thread (676 slots / 512 threads) ----
    int   rowbase[2], gxs[2];
    float* ldsp[2];
    bool  valid[2], edge[2];
    #pragma unroll
    for (int k = 0; k < 2; ++k) {
        int s = tid + NTHR * k;
        valid[k] = (s < NSLOT);
        int ss = valid[k] ? s : 0;
        int r  = ss / 13;
        int c4 = ss - r * 13;
        int gy = y0 + r - PAD;
        gy = (gy < 0) ? -gy : ((gy >= HH) ? (2 * (HH - 1) - gy) : gy);
        int gx = x0 + (c4 << 2) - PAD;
        rowbase[k] = gy * WW;
        gxs[k]     = gx;
        edge[k]    = (gx < 0) || (gx > WW - 4);
        ldsp[k]    = &tile[r][c4 << 2];
    }

    const float* src0 = noisy + (size_t)ch * HW;
    float4 pre[2];
    // prefetch batch 0
    #pragma unroll
    for (int k = 0; k < 2; ++k) {
        if (valid[k]) {
            if (!edge[k]) {
                pre[k] = *(const float4*)(src0 + rowbase[k] + gxs[k]);
            } else {
                float tmp[4];
                #pragma unroll
                for (int t = 0; t < 4; ++t) {
                    int gx = gxs[k] + t;
                    gx = (gx < 0) ? -gx : ((gx >= WW) ? (2 * (WW - 1) - gx) : gx);
                    tmp[t] = src0[rowbase[k] + gx];
                }
                pre[k] = make_float4(tmp[0], tmp[1], tmp[2], tmp[3]);
            }
        }
    }

    float num[2] = {0.f, 0.f};
    float den[2] = {0.f, 0.f};

    const int tx  = tid & 31;
    const int ty0 = (tid >> 5) << 1;       // 2 consecutive output rows / thread
    const float kE = (-100.0f / 441.0f) * 1.44269504088896f;  // fold 1/h^2/n/ln2

    for (int b = 0; b < B; ++b) {
        lds_barrier();                     // Btop: previous V's tile/hs reads done
        #pragma unroll
        for (int k = 0; k < 2; ++k)
            if (valid[k]) *(float4*)ldsp[k] = pre[k];
        lds_barrier();                     // B1: tile visible

        // issue next batch's global loads now; in flight across H+V+Btop
        if (b < B - 1) {
            const float* srcn = noisy + (size_t)((b + 1) * CCH + ch) * HW;
            #pragma unroll
            for (int k = 0; k < 2; ++k) {
                if (valid[k]) {
                    if (!edge[k]) {
                        pre[k] = *(const float4*)(srcn + rowbase[k] + gxs[k]);
                    } else {
                        float tmp[4];
                        #pragma unroll
                        for (int t = 0; t < 4; ++t) {
                            int gx = gxs[k] + t;
                            gx = (gx < 0) ? -gx : ((gx >= WW) ? (2 * (WW - 1) - gx) : gx);
                            tmp[t] = srcn[rowbase[k] + gx];
                        }
                        pre[k] = make_float4(tmp[0], tmp[1], tmp[2], tmp[3]);
                    }
                }
            }
        }

        // ---- horizontal box sums: 52 rows x 8 segments of 4 output cols ----
        if (tid < HTASK) {
            int r   = tid >> 3;
            int cx0 = (tid & 7) << 2;      // 0,4,...,28
            float v[24];
            #pragma unroll
            for (int q = 0; q < 6; ++q)
                *(float4*)&v[q * 4] = *(const float4*)&tile[r][cx0 + (q << 2)];
            float s1 = 0.f, s2 = 0.f;
            #pragma unroll
            for (int k = 0; k <= 20; ++k) { s1 += v[k]; s2 = fmaf(v[k], v[k], s2); }
            hs_t[cx0][r] = make_float2(s1, s2);
            #pragma unroll
            for (int j = 1; j < 4; ++j) {
                float vo = v[j - 1], vn = v[j + 20];
                s1 += vn - vo;
                s2 += vn * vn - vo * vo;
                hs_t[cx0 + j][r] = make_float2(s1, s2);
            }
        }
        lds_barrier();                     // B2: hs visible

        // ---- vertical sliding sums: 2 output rows per thread ----
        float2 h0 = hs_t[tx][ty0];
        float2 h1 = hs_t[tx][ty0 + 1];
        float vs1 = h0.x + h1.x;
        float vs2 = h0.y + h1.y;
        #pragma unroll
        for (int k = 2; k <= 20; ++k) {
            float2 h = hs_t[tx][ty0 + k];
            vs1 += h.x;
            vs2 += h.y;
        }
        {
            float a = tile[ty0 + PAD][tx + PAD];
            float p = tile[ty0][tx];
            float dd = fmaf(a, fmaf(441.f, a, -2.f * vs1), vs2);
            float w = exp2f(dd * kE);
            num[0] += w * p; den[0] += w;
        }
        {
            float2 hn = hs_t[tx][ty0 + 21];
            vs1 += hn.x - h0.x;
            vs2 += hn.y - h0.y;
            float a = tile[ty0 + 1 + PAD][tx + PAD];
            float p = tile[ty0 + 1][tx];
            float dd = fmaf(a, fmaf(441.f, a, -2.f * vs1), vs2);
            float w = exp2f(dd * kE);
            num[1] += w * p; den[1] += w;
        }
    }

    // ---- epilogue: identical value for all 8 batch slices ----
    #pragma unroll
    for (int i = 0; i < 2; ++i) {
        int y = y0 + ty0 + i;
        int x = x0 + tx;
        float v = num[i] / (den[i] + 1e-10f);
        v = v < 0.f ? 0.f : (v > 1.f ? 1.f : v);
        #pragma unroll
        for (int bb = 0; bb < B; ++bb)
            out[((size_t)(bb * CCH + ch) * HH + y) * WW + x] = v;
    }
}

extern "C" void kernel_launch(void* const* d_in, const int* in_sizes, int n_in,
                              void* d_out, int out_size, void* d_ws, size_t ws_size,
                              hipStream_t stream) {
    const float* noisy = (const float*)d_in[0];
    float* out = (float*)d_out;
    dim3 grid(WW / TSX, HH / TSY, CCH);
    nlm_fused_kernel<<<grid, dim3(NTHR), 0, stream>>>(noisy, out);
}